// Round 20
// baseline (133.735 us; speedup 1.0000x reference)
//
#include <hip/hip_runtime.h>
#include <math.h>

#define B_ 4
#define D_ 256
#define N_ 2048
#define H_ 4

typedef __attribute__((ext_vector_type(8))) __bf16 bf16x8;
typedef __attribute__((ext_vector_type(4))) __bf16 bf16x4;
typedef __attribute__((ext_vector_type(4))) float f32x4;

// ---------------------------------------------------------------------------
// Row loaders: 16 contiguous elements -> 2x bf16x8 (cvt only for f32 source).
// ---------------------------------------------------------------------------
__device__ __forceinline__ void load_row16(const float* src, bf16x8* xs) {
    float tmp[16];
    *(float4*)&tmp[0]  = *(const float4*)&src[0];
    *(float4*)&tmp[4]  = *(const float4*)&src[4];
    *(float4*)&tmp[8]  = *(const float4*)&src[8];
    *(float4*)&tmp[12] = *(const float4*)&src[12];
    __bf16* o = (__bf16*)xs;
#pragma unroll
    for (int i = 0; i < 16; ++i) o[i] = (__bf16)tmp[i];
}
__device__ __forceinline__ void load_row16(const __bf16* src, bf16x8* xs) {
    xs[0] = *(const bf16x8*)src;
    xs[1] = *(const bf16x8*)(src + 8);
}

// ---------------------------------------------------------------------------
// MFMA bf16 conv1x1 tile (r8 structure), templated in/out dtypes + out scale.
// ---------------------------------------------------------------------------
template <typename In1T, typename In2T, typename OutT>
__device__ __forceinline__ void conv_tile(
    const In1T* __restrict__ in1, int C1,
    const In2T* __restrict__ in2, int C2,
    const float* __restrict__ Wt, const float* __restrict__ bias,
    OutT* __restrict__ out, int Cout, int K, int RELU, float oscale,
    int b, int o0, int n0, __bf16 (*sXT)[72])
{
    const int t = threadIdx.x;
    const int w  = t >> 6;
    const int g  = (t >> 4) & 3;
    const int c16 = t & 15;
    const int d_ld = t & 63;
    const int xcol = (t >> 6) * 16;

    f32x4 acc[4];
#pragma unroll
    for (int i = 0; i < 4; ++i) acc[i] = (f32x4){0.f, 0.f, 0.f, 0.f};

    bf16x8 xs[2];
    float4 wreg[4];
    const int ow = o0 + 16 * w + c16;

    auto LOADX = [&](int ks) {
        const int ch = ks + d_ld;
        if (ch < C1) load_row16(in1 + ((size_t)b * C1 + ch) * N_ + n0 + xcol, xs);
        else         load_row16(in2 + ((size_t)b * C2 + (ch - C1)) * N_ + n0 + xcol, xs);
    };
    auto LOADW = [&](int ks) {
        wreg[0] = *(const float4*)&Wt[(size_t)ow * K + ks + 8 * g];
        wreg[1] = *(const float4*)&Wt[(size_t)ow * K + ks + 8 * g + 4];
        wreg[2] = *(const float4*)&Wt[(size_t)ow * K + ks + 32 + 8 * g];
        wreg[3] = *(const float4*)&Wt[(size_t)ow * K + ks + 32 + 8 * g + 4];
    };
    auto WRITEXT = [&](int buf) {
        __bf16 (*sx)[72] = sXT + (size_t)buf * 64;
        const __bf16* kp = (const __bf16*)xs;
#pragma unroll
        for (int i = 0; i < 16; ++i)
            sx[xcol + i][d_ld] = kp[i];
    };

    LOADX(0);
    LOADW(0);
    WRITEXT(0);
    __syncthreads();

    const int nsteps = K >> 6;
    for (int s = 0; s < nsteps; ++s) {
        const int cur = s & 1;
        const int ks = s << 6;
        if (s + 1 < nsteps) LOADX(ks + 64);

        bf16x8 af[2];
#pragma unroll
        for (int kc = 0; kc < 2; ++kc) {
            const float* w0 = (const float*)&wreg[2 * kc];
            const float* w1 = (const float*)&wreg[2 * kc + 1];
#pragma unroll
            for (int i = 0; i < 4; ++i) {
                af[kc][i]     = (__bf16)w0[i];
                af[kc][i + 4] = (__bf16)w1[i];
            }
        }
        if (s + 1 < nsteps) LOADW(ks + 64);

        __bf16 (*sx)[72] = sXT + (size_t)cur * 64;
#pragma unroll
        for (int kc = 0; kc < 2; ++kc)
#pragma unroll
            for (int nsub = 0; nsub < 4; ++nsub) {
                const bf16x8 bfr = *(const bf16x8*)&sx[16 * nsub + c16][32 * kc + 8 * g];
                acc[nsub] = __builtin_amdgcn_mfma_f32_16x16x32_bf16(af[kc], bfr, acc[nsub], 0, 0, 0);
            }

        if (s + 1 < nsteps) WRITEXT(cur ^ 1);
        __syncthreads();
    }

#pragma unroll
    for (int nsub = 0; nsub < 4; ++nsub)
#pragma unroll
        for (int r = 0; r < 4; ++r) {
            const int o = o0 + 16 * w + 4 * g + r;
            float v = acc[nsub][r] + bias[o];
            if (RELU) v = fmaxf(v, 0.f);
            v *= oscale;
            out[((size_t)b * Cout + o) * N_ + n0 + 16 * nsub + c16] = (OutT)v;
        }
}

// ---------------------------------------------------------------------------
// Wm conv with FUSED combine: msg[c][n] = (sum_s OP_s) * inv(sum_s L_s).
// (M == 0 for all splits -> combine weights are exactly 1.)
// ---------------------------------------------------------------------------
template <int NS>
__global__ __launch_bounds__(256) void conv_msg_kernel(
    const __bf16* __restrict__ OP, const float* __restrict__ ML,
    const float* __restrict__ Wt, const float* __restrict__ bias,
    __bf16* __restrict__ out)
{
    __shared__ __bf16 sXT[2 * 64][72];
    const int t = threadIdx.x;
    const int w  = t >> 6;
    const int g  = (t >> 4) & 3;
    const int c16 = t & 15;
    const int d_ld = t & 63;
    const int xcol = (t >> 6) * 16;
    const int nt = blockIdx.x;
    const int n0 = nt * 64;
    const int o0 = blockIdx.y * 64;
    const int b  = blockIdx.z;
    const int K = D_, Cout = D_;

    const int h = d_ld & 3;
    const size_t pid0 = ((size_t)(b * H_ + h) * NS) * 32 + nt;

    float invL[16];
#pragma unroll
    for (int i = 0; i < 16; i += 4) {
        float4 a = *(const float4*)&ML[pid0 * 128 + 64 + xcol + i];
#pragma unroll
        for (int s = 1; s < NS; ++s) {
            const float4 c = *(const float4*)&ML[(pid0 + (size_t)s * 32) * 128 + 64 + xcol + i];
            a.x += c.x; a.y += c.y; a.z += c.z; a.w += c.w;
        }
        invL[i + 0] = 1.0f / a.x; invL[i + 1] = 1.0f / a.y;
        invL[i + 2] = 1.0f / a.z; invL[i + 3] = 1.0f / a.w;
    }

    f32x4 acc[4];
#pragma unroll
    for (int i = 0; i < 4; ++i) acc[i] = (f32x4){0.f, 0.f, 0.f, 0.f};

    bf16x8 xs[2];
    float4 wreg[4];
    const int ow = o0 + 16 * w + c16;

    auto LOADX = [&](int ks) {
        const int dd = (ks + d_ld) >> 2;
        float v0[8], v1[8];
#pragma unroll
        for (int i = 0; i < 8; ++i) { v0[i] = 0.f; v1[i] = 0.f; }
#pragma unroll
        for (int s = 0; s < NS; ++s) {
            const __bf16* ps = &OP[(pid0 + (size_t)s * 32) * 4096 + dd * 64 + xcol];
            const bf16x8 a0 = *(const bf16x8*)ps;
            const bf16x8 a1 = *(const bf16x8*)(ps + 8);
#pragma unroll
            for (int i = 0; i < 8; ++i) { v0[i] += (float)a0[i]; v1[i] += (float)a1[i]; }
        }
        __bf16* o = (__bf16*)xs;
#pragma unroll
        for (int i = 0; i < 8; ++i) {
            o[i]     = (__bf16)(v0[i] * invL[i]);
            o[8 + i] = (__bf16)(v1[i] * invL[8 + i]);
        }
    };
    auto LOADW = [&](int ks) {
        wreg[0] = *(const float4*)&Wt[(size_t)ow * K + ks + 8 * g];
        wreg[1] = *(const float4*)&Wt[(size_t)ow * K + ks + 8 * g + 4];
        wreg[2] = *(const float4*)&Wt[(size_t)ow * K + ks + 32 + 8 * g];
        wreg[3] = *(const float4*)&Wt[(size_t)ow * K + ks + 32 + 8 * g + 4];
    };
    auto WRITEXT = [&](int buf) {
        __bf16 (*sx)[72] = sXT + (size_t)buf * 64;
        const __bf16* kp = (const __bf16*)xs;
#pragma unroll
        for (int i = 0; i < 16; ++i)
            sx[xcol + i][d_ld] = kp[i];
    };

    LOADX(0);
    LOADW(0);
    WRITEXT(0);
    __syncthreads();

    const int nsteps = K >> 6;
    for (int s = 0; s < nsteps; ++s) {
        const int cur = s & 1;
        const int ks = s << 6;
        if (s + 1 < nsteps) LOADX(ks + 64);

        bf16x8 af[2];
#pragma unroll
        for (int kc = 0; kc < 2; ++kc) {
            const float* w0 = (const float*)&wreg[2 * kc];
            const float* w1 = (const float*)&wreg[2 * kc + 1];
#pragma unroll
            for (int i = 0; i < 4; ++i) {
                af[kc][i]     = (__bf16)w0[i];
                af[kc][i + 4] = (__bf16)w1[i];
            }
        }
        if (s + 1 < nsteps) LOADW(ks + 64);

        __bf16 (*sx)[72] = sXT + (size_t)cur * 64;
#pragma unroll
        for (int kc = 0; kc < 2; ++kc)
#pragma unroll
            for (int nsub = 0; nsub < 4; ++nsub) {
                const bf16x8 bfr = *(const bf16x8*)&sx[16 * nsub + c16][32 * kc + 8 * g];
                acc[nsub] = __builtin_amdgcn_mfma_f32_16x16x32_bf16(af[kc], bfr, acc[nsub], 0, 0, 0);
            }

        if (s + 1 < nsteps) WRITEXT(cur ^ 1);
        __syncthreads();
    }

#pragma unroll
    for (int nsub = 0; nsub < 4; ++nsub)
#pragma unroll
        for (int r = 0; r < 4; ++r) {
            const int o = o0 + 16 * w + 4 * g + r;
            const float v = acc[nsub][r] + bias[o];
            out[((size_t)b * Cout + o) * N_ + n0 + 16 * nsub + c16] = (__bf16)v;
        }
}

// W1: concat(Xh bf16, MES bf16) -> relu -> H1 bf16
__global__ __launch_bounds__(256) void conv_mix_kernel(
    const __bf16* __restrict__ in1, int C1,
    const __bf16* __restrict__ in2, int C2,
    const float* __restrict__ W, const float* __restrict__ bias,
    __bf16* __restrict__ out, int Cout, int K)
{
    __shared__ __bf16 sXT[2 * 64][72];
    conv_tile<__bf16, __bf16, __bf16>(in1, C1, in2, C2,
        W, bias, out, Cout, K, 1, 1.0f,
        blockIdx.z, blockIdx.y * 64, blockIdx.x * 64, sXT);
}

// W2: H1 bf16 -> out f32
__global__ __launch_bounds__(256) void conv_hf_kernel(
    const __bf16* __restrict__ in1, const float* __restrict__ W,
    const float* __restrict__ bias, float* __restrict__ out, int Cout, int K)
{
    __shared__ __bf16 sXT[2 * 64][72];
    conv_tile<__bf16, __bf16, float>(in1, K, (const __bf16*)nullptr, 0,
        W, bias, out, Cout, K, 0, 1.0f,
        blockIdx.z, blockIdx.y * 64, blockIdx.x * 64, sXT);
}

// ---------------------------------------------------------------------------
// Fused Q/K/V projections (y<12) + x -> bf16 convert ride-along (y==12).
// K pre-scaled by 0.125*log2(e) for exp2 softmax.
// ---------------------------------------------------------------------------
__global__ __launch_bounds__(256) void qkv_conv_kernel(
    const float* __restrict__ x, const float* __restrict__ source,
    const float* __restrict__ Wq, const float* __restrict__ bq,
    const float* __restrict__ Wk, const float* __restrict__ bk,
    const float* __restrict__ Wv, const float* __restrict__ bv,
    __bf16* __restrict__ Qo, __bf16* __restrict__ Ko, __bf16* __restrict__ Vo,
    __bf16* __restrict__ Xh)
{
    if (blockIdx.y == 12) {
        const int slot = blockIdx.x * 4 + blockIdx.z;
        const size_t base = (size_t)slot * 16384;
#pragma unroll
        for (int j = 0; j < 16; ++j) {
            const size_t idx = base + j * 1024 + threadIdx.x * 4;
            const float4 v = *(const float4*)&x[idx];
            bf16x4 o;
            o[0] = (__bf16)v.x; o[1] = (__bf16)v.y;
            o[2] = (__bf16)v.z; o[3] = (__bf16)v.w;
            *(bf16x4*)&Xh[idx] = o;
        }
        return;
    }
    __shared__ __bf16 sXT[2 * 64][72];
    const int sel = blockIdx.y >> 2;
    const int o0  = (blockIdx.y & 3) * 64;
    const float* in = (sel == 0) ? x : source;
    const float* W  = (sel == 0) ? Wq : (sel == 1) ? Wk : Wv;
    const float* bs = (sel == 0) ? bq : (sel == 1) ? bk : bv;
    __bf16* out     = (sel == 0) ? Qo : (sel == 1) ? Ko : Vo;
    const float sc  = (sel == 1) ? 0.125f * 1.4426950408889634f : 1.0f;
    conv_tile<float, float, __bf16>(in, D_, (const float*)nullptr, 0,
        W, bs, out, D_, D_, 0, sc,
        blockIdx.z, o0, blockIdx.x * 64, sXT);
}

// ---------------------------------------------------------------------------
// MFMA bf16 fused attention: m-split flash, no-max exp2 softmax, coalesced K
// staging, block-granular XOR swizzle. SINGLE-buffered sKT/sP (18.4 KB LDS,
// 2 barriers/tile — measured equal to dbuf) so 8 blocks/CU fit at NSPLIT=4.
// Plain launch_bounds(256): natural VGPR (~64), no forced cap (r9 lesson).
// ---------------------------------------------------------------------------
template <int NSPLIT>
__global__ __launch_bounds__(256) void attn_kernel(
    const __bf16* __restrict__ Qg, const __bf16* __restrict__ Kg,
    const __bf16* __restrict__ Vg, const float* __restrict__ Eg,
    __bf16* __restrict__ OP, float* __restrict__ ML)
{
    const int nt    = blockIdx.x;
    const int n0    = nt * 64;
    const int split = blockIdx.y % NSPLIT;
    const int h     = blockIdx.y / NSPLIT;
    const int b     = blockIdx.z;
    const int t  = threadIdx.x;
    const int w  = t >> 6;
    const int g  = (t >> 4) & 3;
    const int c16 = t & 15;

    const int MT   = 32 / NSPLIT;
    const int m_lo = split * (N_ / NSPLIT);
    const int pid  = ((b * H_ + h) * NSPLIT + split) * 32 + nt;

    __shared__ __bf16 sKT[64][72];  // K^T [m][d], swizzled, single buffer
    __shared__ __bf16 sP [64][72];  // P [n][m], swizzled, single buffer

    bf16x8 qf[2];
#pragma unroll
    for (int kc = 0; kc < 2; ++kc)
#pragma unroll
        for (int e = 0; e < 8; ++e) {
            const int d = 32 * kc + 8 * g + e;
            qf[kc][e] = Qg[((size_t)b * D_ + d * H_ + h) * N_ + n0 + 16 * w + c16];
        }

    f32x4 acc[4];
#pragma unroll
    for (int i = 0; i < 4; ++i) acc[i] = (f32x4){0.f, 0.f, 0.f, 0.f};
    float Lr[4];
#pragma unroll
    for (int r = 0; r < 4; ++r) Lr[r] = 0.f;

    const int kd = t >> 2;
    const int km = (t & 3) * 16;
    const size_t kbase = ((size_t)b * D_ + kd * H_ + h) * N_ + m_lo + km;
    const size_t vrow  = ((size_t)b * D_ + (16 * w + c16) * H_ + h) * N_ + m_lo;
    const size_t ebase = ((size_t)b * N_ + n0 + 16 * w + 4 * g) * N_ + m_lo + c16;

    bf16x8 kreg[2];
    bf16x8 vreg[2];
    float  ereg[4][4];

    auto LOADK = [&](int m0) {
        kreg[0] = *(const bf16x8*)&Kg[kbase + m0];
        kreg[1] = *(const bf16x8*)&Kg[kbase + m0 + 8];
    };
    auto LOADV = [&](int m0) {
        vreg[0] = *(const bf16x8*)&Vg[vrow + m0 + 8 * g];
        vreg[1] = *(const bf16x8*)&Vg[vrow + m0 + 32 + 8 * g];
    };
    auto LOADE = [&](int m0) {
#pragma unroll
        for (int r = 0; r < 4; ++r)
#pragma unroll
            for (int ms = 0; ms < 4; ++ms)
                ereg[r][ms] = Eg[ebase + (size_t)r * N_ + m0 + 16 * ms];
    };
    const int kcb = kd >> 3, kcw = kd & 7;
    auto WRITEKT = [&]() {
        const __bf16* kp = (const __bf16*)kreg;
#pragma unroll
        for (int i = 0; i < 16; ++i) {
            const int m = km + i;
            sKT[m][(((kcb ^ ((m >> 3) & 7)) << 3) | kcw)] = kp[i];
        }
    };

    LOADK(0);
    LOADV(0);
    LOADE(0);
    WRITEKT();
    __syncthreads();

    for (int mt = 0; mt < MT; ++mt) {
        const int m0n = (mt < MT - 1 ? mt + 1 : mt) * 64;

        const bf16x8 af0 = vreg[0], af1 = vreg[1];
        LOADK(m0n);
        LOADV(m0n);

        // ---- QK^T from sKT (swizzled) ----
        f32x4 sfrag[4];
#pragma unroll
        for (int msub = 0; msub < 4; ++msub) {
            const int m   = 16 * msub + c16;
            const int swz = (m >> 3) & 7;
            f32x4 s = (f32x4){0.f, 0.f, 0.f, 0.f};
#pragma unroll
            for (int kc = 0; kc < 2; ++kc) {
                const bf16x8 bfr = *(const bf16x8*)&sKT[m][((4 * kc + g) ^ swz) << 3];
                s = __builtin_amdgcn_mfma_f32_16x16x32_bf16(qf[kc], bfr, s, 0, 0, 0);
            }
            sfrag[msub] = s;
        }

        // ---- p = exp2(s), L += p, sP swizzled write ----
        {
            const int pc_hi = c16 >> 3, pc_lo = c16 & 7;
#pragma unroll
            for (int msub = 0; msub < 4; ++msub) {
#pragma unroll
                for (int r = 0; r < 4; ++r) {
                    const int nloc = 16 * w + 4 * g + r;
                    const int swz  = (nloc >> 3) & 7;
                    const float p = exp2f(sfrag[msub][r]);
                    Lr[r] += p;
                    sP[nloc][((((2 * msub + pc_hi) ^ swz) << 3) | pc_lo)] =
                        (__bf16)(p * ereg[r][msub]);
                }
            }
        }
        LOADE(m0n);

        __syncthreads();  // D: sP ready; all sKT reads done

        // ---- PV from sP (swizzled) ----
#pragma unroll
        for (int nsub = 0; nsub < 4; ++nsub) {
            const int row = 16 * nsub + c16;
            const int swz = (row >> 3) & 7;
            const bf16x8 b0 = *(const bf16x8*)&sP[row][(g ^ swz) << 3];
            acc[nsub] = __builtin_amdgcn_mfma_f32_16x16x32_bf16(af0, b0, acc[nsub], 0, 0, 0);
            const bf16x8 b1 = *(const bf16x8*)&sP[row][((4 + g) ^ swz) << 3];
            acc[nsub] = __builtin_amdgcn_mfma_f32_16x16x32_bf16(af1, b1, acc[nsub], 0, 0, 0);
        }
        WRITEKT();

        __syncthreads();  // F: sKT(t+1) visible; all sP reads done
    }

    // epilogue: reduce L over 16 lanes, store partials (M stored as 0)
#pragma unroll
    for (int mask = 1; mask < 16; mask <<= 1)
#pragma unroll
        for (int r = 0; r < 4; ++r) Lr[r] += __shfl_xor(Lr[r], mask);
    if (c16 == 0) {
#pragma unroll
        for (int r = 0; r < 4; ++r) {
            const int nloc = 16 * w + 4 * g + r;
            ML[(size_t)pid * 128 + nloc]      = 0.0f;
            ML[(size_t)pid * 128 + 64 + nloc] = Lr[r];
        }
    }
#pragma unroll
    for (int nsub = 0; nsub < 4; ++nsub)
#pragma unroll
        for (int r = 0; r < 4; ++r) {
            const int dd = 16 * w + 4 * g + r;
            OP[(size_t)pid * 4096 + dd * 64 + 16 * nsub + c16] = (__bf16)acc[nsub][r];
        }
}

// ---------------------------------------------------------------------------
extern "C" void kernel_launch(void* const* d_in, const int* in_sizes, int n_in,
                              void* d_out, int out_size, void* d_ws, size_t ws_size,
                              hipStream_t stream) {
    const float* x      = (const float*)d_in[0];
    const float* source = (const float*)d_in[1];
    const float* edge   = (const float*)d_in[2];
    const float* Wq = (const float*)d_in[3];
    const float* bq = (const float*)d_in[4];
    const float* Wk = (const float*)d_in[5];
    const float* bk = (const float*)d_in[6];
    const float* Wv = (const float*)d_in[7];
    const float* bv = (const float*)d_in[8];
    const float* Wm = (const float*)d_in[9];
    const float* bm = (const float*)d_in[10];
    const float* W1 = (const float*)d_in[11];
    const float* b1 = (const float*)d_in[12];
    const float* W2 = (const float*)d_in[13];
    const float* b2 = (const float*)d_in[14];
    float* out = (float*)d_out;

    const size_t BDN = (size_t)B_ * D_ * N_;
    char* p = (char*)d_ws;
    __bf16* Qh  = (__bf16*)(p);
    __bf16* Kh  = (__bf16*)(p + 2 * BDN);
    __bf16* Vh  = (__bf16*)(p + 4 * BDN);
    __bf16* MES = (__bf16*)(p + 6 * BDN);
    __bf16* H1  = (__bf16*)(p + 8 * BDN);    // 2*BDN bf16 = 4*BDN bytes
    __bf16* Xh  = (__bf16*)(p + 12 * BDN);   // x as bf16
    char*   tail = p + 14 * BDN;
    const size_t baseBytes = 14 * BDN;

    const dim3 blk(256);
    const dim3 gD(N_ / 64, D_ / 64, B_);
    const dim3 g2D(N_ / 64, 2 * D_ / 64, B_);

    auto needFor = [&](int ns) {
        const size_t pids = (size_t)ns * B_ * H_ * 32;
        return baseBytes + pids * 4096 * 2 + pids * 128 * 4;
    };

    const int NS = (ws_size >= needFor(4)) ? 4 : (ws_size >= needFor(2)) ? 2 : 1;
    const size_t pids = (size_t)NS * B_ * H_ * 32;
    __bf16* OP = (__bf16*)tail;
    float*  ML = (float*)(tail + pids * 4096 * 2);

    // 1) Q/K/V projections + x->bf16 ride-along
    qkv_conv_kernel<<<dim3(N_ / 64, 13, B_), blk, 0, stream>>>(
        x, source, Wq, bq, Wk, bk, Wv, bv, Qh, Kh, Vh, Xh);

    // 2) attention -> partials; 3) Wm conv with fused combine
    if (NS == 4) {
        attn_kernel<4><<<dim3(32, H_ * 4, B_), blk, 0, stream>>>(Qh, Kh, Vh, edge, OP, ML);
        conv_msg_kernel<4><<<gD, blk, 0, stream>>>(OP, ML, Wm, bm, MES);
    } else if (NS == 2) {
        attn_kernel<2><<<dim3(32, H_ * 2, B_), blk, 0, stream>>>(Qh, Kh, Vh, edge, OP, ML);
        conv_msg_kernel<2><<<gD, blk, 0, stream>>>(OP, ML, Wm, bm, MES);
    } else {
        attn_kernel<1><<<dim3(32, H_, B_), blk, 0, stream>>>(Qh, Kh, Vh, edge, OP, ML);
        conv_msg_kernel<1><<<gD, blk, 0, stream>>>(OP, ML, Wm, bm, MES);
    }

    // 4) MLP (x read as bf16)
    conv_mix_kernel<<<g2D, blk, 0, stream>>>(Xh, D_, MES, D_, W1, b1, H1, 2 * D_, 2 * D_);
    conv_hf_kernel<<<gD, blk, 0, stream>>>(H1, W2, b2, out, D_, 2 * D_);
}

// Round 21
// 126.546 us; speedup vs baseline: 1.0568x; 1.0568x over previous
//
#include <hip/hip_runtime.h>
#include <math.h>

#define B_ 4
#define D_ 256
#define N_ 2048
#define H_ 4

typedef __attribute__((ext_vector_type(8))) __bf16 bf16x8;
typedef __attribute__((ext_vector_type(4))) __bf16 bf16x4;
typedef __attribute__((ext_vector_type(4))) float f32x4;

// ---------------------------------------------------------------------------
// Row loaders: 16 contiguous elements -> 2x bf16x8 (cvt only for f32 source).
// ---------------------------------------------------------------------------
__device__ __forceinline__ void load_row16(const float* src, bf16x8* xs) {
    float tmp[16];
    *(float4*)&tmp[0]  = *(const float4*)&src[0];
    *(float4*)&tmp[4]  = *(const float4*)&src[4];
    *(float4*)&tmp[8]  = *(const float4*)&src[8];
    *(float4*)&tmp[12] = *(const float4*)&src[12];
    __bf16* o = (__bf16*)xs;
#pragma unroll
    for (int i = 0; i < 16; ++i) o[i] = (__bf16)tmp[i];
}
__device__ __forceinline__ void load_row16(const __bf16* src, bf16x8* xs) {
    xs[0] = *(const bf16x8*)src;
    xs[1] = *(const bf16x8*)(src + 8);
}

// ---------------------------------------------------------------------------
// MFMA bf16 conv1x1 tile (r8 structure), templated in/out dtypes + out scale.
// ---------------------------------------------------------------------------
template <typename In1T, typename In2T, typename OutT>
__device__ __forceinline__ void conv_tile(
    const In1T* __restrict__ in1, int C1,
    const In2T* __restrict__ in2, int C2,
    const float* __restrict__ Wt, const float* __restrict__ bias,
    OutT* __restrict__ out, int Cout, int K, int RELU, float oscale,
    int b, int o0, int n0, __bf16 (*sXT)[72])
{
    const int t = threadIdx.x;
    const int w  = t >> 6;
    const int g  = (t >> 4) & 3;
    const int c16 = t & 15;
    const int d_ld = t & 63;
    const int xcol = (t >> 6) * 16;

    f32x4 acc[4];
#pragma unroll
    for (int i = 0; i < 4; ++i) acc[i] = (f32x4){0.f, 0.f, 0.f, 0.f};

    bf16x8 xs[2];
    float4 wreg[4];
    const int ow = o0 + 16 * w + c16;

    auto LOADX = [&](int ks) {
        const int ch = ks + d_ld;
        if (ch < C1) load_row16(in1 + ((size_t)b * C1 + ch) * N_ + n0 + xcol, xs);
        else         load_row16(in2 + ((size_t)b * C2 + (ch - C1)) * N_ + n0 + xcol, xs);
    };
    auto LOADW = [&](int ks) {
        wreg[0] = *(const float4*)&Wt[(size_t)ow * K + ks + 8 * g];
        wreg[1] = *(const float4*)&Wt[(size_t)ow * K + ks + 8 * g + 4];
        wreg[2] = *(const float4*)&Wt[(size_t)ow * K + ks + 32 + 8 * g];
        wreg[3] = *(const float4*)&Wt[(size_t)ow * K + ks + 32 + 8 * g + 4];
    };
    auto WRITEXT = [&](int buf) {
        __bf16 (*sx)[72] = sXT + (size_t)buf * 64;
        const __bf16* kp = (const __bf16*)xs;
#pragma unroll
        for (int i = 0; i < 16; ++i)
            sx[xcol + i][d_ld] = kp[i];
    };

    LOADX(0);
    LOADW(0);
    WRITEXT(0);
    __syncthreads();

    const int nsteps = K >> 6;
    for (int s = 0; s < nsteps; ++s) {
        const int cur = s & 1;
        const int ks = s << 6;
        if (s + 1 < nsteps) LOADX(ks + 64);

        bf16x8 af[2];
#pragma unroll
        for (int kc = 0; kc < 2; ++kc) {
            const float* w0 = (const float*)&wreg[2 * kc];
            const float* w1 = (const float*)&wreg[2 * kc + 1];
#pragma unroll
            for (int i = 0; i < 4; ++i) {
                af[kc][i]     = (__bf16)w0[i];
                af[kc][i + 4] = (__bf16)w1[i];
            }
        }
        if (s + 1 < nsteps) LOADW(ks + 64);

        __bf16 (*sx)[72] = sXT + (size_t)cur * 64;
#pragma unroll
        for (int kc = 0; kc < 2; ++kc)
#pragma unroll
            for (int nsub = 0; nsub < 4; ++nsub) {
                const bf16x8 bfr = *(const bf16x8*)&sx[16 * nsub + c16][32 * kc + 8 * g];
                acc[nsub] = __builtin_amdgcn_mfma_f32_16x16x32_bf16(af[kc], bfr, acc[nsub], 0, 0, 0);
            }

        if (s + 1 < nsteps) WRITEXT(cur ^ 1);
        __syncthreads();
    }

#pragma unroll
    for (int nsub = 0; nsub < 4; ++nsub)
#pragma unroll
        for (int r = 0; r < 4; ++r) {
            const int o = o0 + 16 * w + 4 * g + r;
            float v = acc[nsub][r] + bias[o];
            if (RELU) v = fmaxf(v, 0.f);
            v *= oscale;
            out[((size_t)b * Cout + o) * N_ + n0 + 16 * nsub + c16] = (OutT)v;
        }
}

// ---------------------------------------------------------------------------
// Wm conv with FUSED combine (r18): msg[c][n] = (OP0+OP1) * inv(L0+L1).
// (M == 0 for both splits, so combine weights are exactly 1.)  Per thread
// h = d_ld&3 is K-step-invariant -> pid and the 16 invL values are
// loop-invariant registers.
// ---------------------------------------------------------------------------
template <int NS>
__global__ __launch_bounds__(256) void conv_msg_kernel(
    const __bf16* __restrict__ OP, const float* __restrict__ ML,
    const float* __restrict__ Wt, const float* __restrict__ bias,
    __bf16* __restrict__ out)
{
    __shared__ __bf16 sXT[2 * 64][72];
    const int t = threadIdx.x;
    const int w  = t >> 6;
    const int g  = (t >> 4) & 3;
    const int c16 = t & 15;
    const int d_ld = t & 63;
    const int xcol = (t >> 6) * 16;
    const int nt = blockIdx.x;
    const int n0 = nt * 64;
    const int o0 = blockIdx.y * 64;
    const int b  = blockIdx.z;
    const int K = D_, Cout = D_;

    const int h = d_ld & 3;
    const size_t pid0 = ((size_t)(b * H_ + h) * NS) * 32 + nt;

    float invL[16];
#pragma unroll
    for (int i = 0; i < 16; i += 4) {
        float4 a = *(const float4*)&ML[pid0 * 128 + 64 + xcol + i];
        if (NS == 2) {
            const float4 c = *(const float4*)&ML[(pid0 + 32) * 128 + 64 + xcol + i];
            a.x += c.x; a.y += c.y; a.z += c.z; a.w += c.w;
        }
        invL[i + 0] = 1.0f / a.x; invL[i + 1] = 1.0f / a.y;
        invL[i + 2] = 1.0f / a.z; invL[i + 3] = 1.0f / a.w;
    }

    f32x4 acc[4];
#pragma unroll
    for (int i = 0; i < 4; ++i) acc[i] = (f32x4){0.f, 0.f, 0.f, 0.f};

    bf16x8 xs[2];
    float4 wreg[4];
    const int ow = o0 + 16 * w + c16;

    auto LOADX = [&](int ks) {
        const int dd = (ks + d_ld) >> 2;
        const __bf16* p0 = &OP[pid0 * 4096 + dd * 64 + xcol];
        const bf16x8 a0 = *(const bf16x8*)p0;
        const bf16x8 a1 = *(const bf16x8*)(p0 + 8);
        bf16x8 b0, b1;
        if (NS == 2) {
            const __bf16* p1 = &OP[(pid0 + 32) * 4096 + dd * 64 + xcol];
            b0 = *(const bf16x8*)p1;
            b1 = *(const bf16x8*)(p1 + 8);
        }
        __bf16* o = (__bf16*)xs;
#pragma unroll
        for (int i = 0; i < 8; ++i) {
            float v = (float)a0[i];
            if (NS == 2) v += (float)b0[i];
            o[i] = (__bf16)(v * invL[i]);
        }
#pragma unroll
        for (int i = 0; i < 8; ++i) {
            float v = (float)a1[i];
            if (NS == 2) v += (float)b1[i];
            o[8 + i] = (__bf16)(v * invL[8 + i]);
        }
    };
    auto LOADW = [&](int ks) {
        wreg[0] = *(const float4*)&Wt[(size_t)ow * K + ks + 8 * g];
        wreg[1] = *(const float4*)&Wt[(size_t)ow * K + ks + 8 * g + 4];
        wreg[2] = *(const float4*)&Wt[(size_t)ow * K + ks + 32 + 8 * g];
        wreg[3] = *(const float4*)&Wt[(size_t)ow * K + ks + 32 + 8 * g + 4];
    };
    auto WRITEXT = [&](int buf) {
        __bf16 (*sx)[72] = sXT + (size_t)buf * 64;
        const __bf16* kp = (const __bf16*)xs;
#pragma unroll
        for (int i = 0; i < 16; ++i)
            sx[xcol + i][d_ld] = kp[i];
    };

    LOADX(0);
    LOADW(0);
    WRITEXT(0);
    __syncthreads();

    const int nsteps = K >> 6;
    for (int s = 0; s < nsteps; ++s) {
        const int cur = s & 1;
        const int ks = s << 6;
        if (s + 1 < nsteps) LOADX(ks + 64);

        bf16x8 af[2];
#pragma unroll
        for (int kc = 0; kc < 2; ++kc) {
            const float* w0 = (const float*)&wreg[2 * kc];
            const float* w1 = (const float*)&wreg[2 * kc + 1];
#pragma unroll
            for (int i = 0; i < 4; ++i) {
                af[kc][i]     = (__bf16)w0[i];
                af[kc][i + 4] = (__bf16)w1[i];
            }
        }
        if (s + 1 < nsteps) LOADW(ks + 64);

        __bf16 (*sx)[72] = sXT + (size_t)cur * 64;
#pragma unroll
        for (int kc = 0; kc < 2; ++kc)
#pragma unroll
            for (int nsub = 0; nsub < 4; ++nsub) {
                const bf16x8 bfr = *(const bf16x8*)&sx[16 * nsub + c16][32 * kc + 8 * g];
                acc[nsub] = __builtin_amdgcn_mfma_f32_16x16x32_bf16(af[kc], bfr, acc[nsub], 0, 0, 0);
            }

        if (s + 1 < nsteps) WRITEXT(cur ^ 1);
        __syncthreads();
    }

#pragma unroll
    for (int nsub = 0; nsub < 4; ++nsub)
#pragma unroll
        for (int r = 0; r < 4; ++r) {
            const int o = o0 + 16 * w + 4 * g + r;
            const float v = acc[nsub][r] + bias[o];
            out[((size_t)b * Cout + o) * N_ + n0 + 16 * nsub + c16] = (__bf16)v;
        }
}

// W1: concat(x f32, MES bf16) -> relu -> H1 bf16
__global__ __launch_bounds__(256) void conv_mix_kernel(
    const float* __restrict__ in1, int C1,
    const __bf16* __restrict__ in2, int C2,
    const float* __restrict__ W, const float* __restrict__ bias,
    __bf16* __restrict__ out, int Cout, int K)
{
    __shared__ __bf16 sXT[2 * 64][72];
    conv_tile<float, __bf16, __bf16>(in1, C1, in2, C2,
        W, bias, out, Cout, K, 1, 1.0f,
        blockIdx.z, blockIdx.y * 64, blockIdx.x * 64, sXT);
}

// W2: H1 bf16 -> out f32
__global__ __launch_bounds__(256) void conv_hf_kernel(
    const __bf16* __restrict__ in1, const float* __restrict__ W,
    const float* __restrict__ bias, float* __restrict__ out, int Cout, int K)
{
    __shared__ __bf16 sXT[2 * 64][72];
    conv_tile<__bf16, __bf16, float>(in1, K, (const __bf16*)nullptr, 0,
        W, bias, out, Cout, K, 0, 1.0f,
        blockIdx.z, blockIdx.y * 64, blockIdx.x * 64, sXT);
}

// Fused Q/K/V projections: f32 in -> bf16 out.
// K pre-scaled by 0.125 * log2(e) so attention can use exp2 directly.
__global__ __launch_bounds__(256) void qkv_conv_kernel(
    const float* __restrict__ x, const float* __restrict__ source,
    const float* __restrict__ Wq, const float* __restrict__ bq,
    const float* __restrict__ Wk, const float* __restrict__ bk,
    const float* __restrict__ Wv, const float* __restrict__ bv,
    __bf16* __restrict__ Qo, __bf16* __restrict__ Ko, __bf16* __restrict__ Vo)
{
    __shared__ __bf16 sXT[2 * 64][72];
    const int sel = blockIdx.y >> 2;
    const int o0  = (blockIdx.y & 3) * 64;
    const float* in = (sel == 0) ? x : source;
    const float* W  = (sel == 0) ? Wq : (sel == 1) ? Wk : Wv;
    const float* bs = (sel == 0) ? bq : (sel == 1) ? bk : bv;
    __bf16* out     = (sel == 0) ? Qo : (sel == 1) ? Ko : Vo;
    const float sc  = (sel == 1) ? 0.125f * 1.4426950408889634f : 1.0f;
    conv_tile<float, float, __bf16>(in, D_, (const float*)nullptr, 0,
        W, bs, out, D_, D_, 0, sc,
        blockIdx.z, o0, blockIdx.x * 64, sXT);
}

// ---------------------------------------------------------------------------
// MFMA bf16 fused attention (r15-exact): m-split flash, no-max exp2 softmax,
// single barrier/tile (dbuf sKT+sP), block-granular XOR swizzle both arrays.
// ---------------------------------------------------------------------------
template <int NSPLIT>
__global__ __launch_bounds__(256, 4) void attn_kernel(
    const __bf16* __restrict__ Qg, const __bf16* __restrict__ Kg,
    const __bf16* __restrict__ Vg, const float* __restrict__ Eg,
    __bf16* __restrict__ OP, float* __restrict__ ML)
{
    const int nt    = blockIdx.x;
    const int n0    = nt * 64;
    const int split = blockIdx.y % NSPLIT;
    const int h     = blockIdx.y / NSPLIT;
    const int b     = blockIdx.z;
    const int t  = threadIdx.x;
    const int w  = t >> 6;
    const int g  = (t >> 4) & 3;
    const int c16 = t & 15;

    const int MT   = 32 / NSPLIT;
    const int m_lo = split * (N_ / NSPLIT);
    const int pid  = ((b * H_ + h) * NSPLIT + split) * 32 + nt;

    __shared__ __bf16 sKT[2][64][72];
    __shared__ __bf16 sP [2][64][72];

    bf16x8 qf[2];
#pragma unroll
    for (int kc = 0; kc < 2; ++kc)
#pragma unroll
        for (int e = 0; e < 8; ++e) {
            const int d = 32 * kc + 8 * g + e;
            qf[kc][e] = Qg[((size_t)b * D_ + d * H_ + h) * N_ + n0 + 16 * w + c16];
        }

    f32x4 acc[4];
#pragma unroll
    for (int i = 0; i < 4; ++i) acc[i] = (f32x4){0.f, 0.f, 0.f, 0.f};
    float Lr[4];
#pragma unroll
    for (int r = 0; r < 4; ++r) Lr[r] = 0.f;

    const int kd = t >> 2;
    const int km = (t & 3) * 16;
    const size_t kbase = ((size_t)b * D_ + kd * H_ + h) * N_ + m_lo + km;
    const size_t vrow  = ((size_t)b * D_ + (16 * w + c16) * H_ + h) * N_ + m_lo;
    const size_t ebase = ((size_t)b * N_ + n0 + 16 * w + 4 * g) * N_ + m_lo + c16;

    bf16x8 kreg[2];
    bf16x8 vreg[2];
    float  ereg[4][4];

    auto LOADK = [&](int m0) {
        kreg[0] = *(const bf16x8*)&Kg[kbase + m0];
        kreg[1] = *(const bf16x8*)&Kg[kbase + m0 + 8];
    };
    auto LOADV = [&](int m0) {
        vreg[0] = *(const bf16x8*)&Vg[vrow + m0 + 8 * g];
        vreg[1] = *(const bf16x8*)&Vg[vrow + m0 + 32 + 8 * g];
    };
    auto LOADE = [&](int m0) {
#pragma unroll
        for (int r = 0; r < 4; ++r)
#pragma unroll
            for (int ms = 0; ms < 4; ++ms)
                ereg[r][ms] = Eg[ebase + (size_t)r * N_ + m0 + 16 * ms];
    };
    const int kcb = kd >> 3, kcw = kd & 7;
    auto WRITEKT = [&](int buf) {
        const __bf16* kp = (const __bf16*)kreg;
#pragma unroll
        for (int i = 0; i < 16; ++i) {
            const int m = km + i;
            sKT[buf][m][(((kcb ^ ((m >> 3) & 7)) << 3) | kcw)] = kp[i];
        }
    };

    LOADK(0);
    LOADV(0);
    LOADE(0);
    WRITEKT(0);
    __syncthreads();

    for (int mt = 0; mt < MT; ++mt) {
        const int cur = mt & 1;
        const int m0n = (mt < MT - 1 ? mt + 1 : mt) * 64;

        const bf16x8 af0 = vreg[0], af1 = vreg[1];
        LOADK(m0n);
        LOADV(m0n);

        f32x4 sfrag[4];
#pragma unroll
        for (int msub = 0; msub < 4; ++msub) {
            const int m   = 16 * msub + c16;
            const int swz = (m >> 3) & 7;
            f32x4 s = (f32x4){0.f, 0.f, 0.f, 0.f};
#pragma unroll
            for (int kc = 0; kc < 2; ++kc) {
                const bf16x8 bfr = *(const bf16x8*)&sKT[cur][m][((4 * kc + g) ^ swz) << 3];
                s = __builtin_amdgcn_mfma_f32_16x16x32_bf16(qf[kc], bfr, s, 0, 0, 0);
            }
            sfrag[msub] = s;
        }

        {
            const int pc_hi = c16 >> 3, pc_lo = c16 & 7;
#pragma unroll
            for (int msub = 0; msub < 4; ++msub) {
#pragma unroll
                for (int r = 0; r < 4; ++r) {
                    const int nloc = 16 * w + 4 * g + r;
                    const int swz  = (nloc >> 3) & 7;
                    const float p = exp2f(sfrag[msub][r]);
                    Lr[r] += p;
                    sP[cur][nloc][((((2 * msub + pc_hi) ^ swz) << 3) | pc_lo)] =
                        (__bf16)(p * ereg[r][msub]);
                }
            }
        }
        LOADE(m0n);

        WRITEKT(cur ^ 1);
        __syncthreads();

#pragma unroll
        for (int nsub = 0; nsub < 4; ++nsub) {
            const int row = 16 * nsub + c16;
            const int swz = (row >> 3) & 7;
            const bf16x8 b0 = *(const bf16x8*)&sP[cur][row][(g ^ swz) << 3];
            acc[nsub] = __builtin_amdgcn_mfma_f32_16x16x32_bf16(af0, b0, acc[nsub], 0, 0, 0);
            const bf16x8 b1 = *(const bf16x8*)&sP[cur][row][((4 + g) ^ swz) << 3];
            acc[nsub] = __builtin_amdgcn_mfma_f32_16x16x32_bf16(af1, b1, acc[nsub], 0, 0, 0);
        }
    }

#pragma unroll
    for (int mask = 1; mask < 16; mask <<= 1)
#pragma unroll
        for (int r = 0; r < 4; ++r) Lr[r] += __shfl_xor(Lr[r], mask);
    if (c16 == 0) {
#pragma unroll
        for (int r = 0; r < 4; ++r) {
            const int nloc = 16 * w + 4 * g + r;
            ML[(size_t)pid * 128 + nloc]      = 0.0f;
            ML[(size_t)pid * 128 + 64 + nloc] = Lr[r];
        }
    }
#pragma unroll
    for (int nsub = 0; nsub < 4; ++nsub)
#pragma unroll
        for (int r = 0; r < 4; ++r) {
            const int dd = 16 * w + 4 * g + r;
            OP[(size_t)pid * 4096 + dd * 64 + 16 * nsub + c16] = (__bf16)acc[nsub][r];
        }
}

// ---------------------------------------------------------------------------
extern "C" void kernel_launch(void* const* d_in, const int* in_sizes, int n_in,
                              void* d_out, int out_size, void* d_ws, size_t ws_size,
                              hipStream_t stream) {
    const float* x      = (const float*)d_in[0];
    const float* source = (const float*)d_in[1];
    const float* edge   = (const float*)d_in[2];
    const float* Wq = (const float*)d_in[3];
    const float* bq = (const float*)d_in[4];
    const float* Wk = (const float*)d_in[5];
    const float* bk = (const float*)d_in[6];
    const float* Wv = (const float*)d_in[7];
    const float* bv = (const float*)d_in[8];
    const float* Wm = (const float*)d_in[9];
    const float* bm = (const float*)d_in[10];
    const float* W1 = (const float*)d_in[11];
    const float* b1 = (const float*)d_in[12];
    const float* W2 = (const float*)d_in[13];
    const float* b2 = (const float*)d_in[14];
    float* out = (float*)d_out;

    const size_t BDN = (size_t)B_ * D_ * N_;
    char* p = (char*)d_ws;
    __bf16* Qh  = (__bf16*)(p);
    __bf16* Kh  = (__bf16*)(p + 2 * BDN);
    __bf16* Vh  = (__bf16*)(p + 4 * BDN);
    __bf16* MES = (__bf16*)(p + 6 * BDN);
    __bf16* H1  = (__bf16*)(p + 8 * BDN);    // 2*BDN bf16 = 4*BDN bytes
    char*   tail = p + 12 * BDN;
    const size_t baseBytes = 12 * BDN;

    const dim3 blk(256);
    const dim3 gD(N_ / 64, D_ / 64, B_);
    const dim3 g2D(N_ / 64, 2 * D_ / 64, B_);

    auto needFor = [&](int ns) {
        const size_t pids = (size_t)ns * B_ * H_ * 32;
        return baseBytes + pids * 4096 * 2 + pids * 128 * 4;
    };

    const int NS = (ws_size >= needFor(2)) ? 2 : 1;
    const size_t pids = (size_t)NS * B_ * H_ * 32;
    __bf16* OP = (__bf16*)tail;
    float*  ML = (float*)(tail + pids * 4096 * 2);

    // 1) Q/K/V projections
    qkv_conv_kernel<<<dim3(N_ / 64, 12, B_), blk, 0, stream>>>(
        x, source, Wq, bq, Wk, bk, Wv, bv, Qh, Kh, Vh);

    // 2) attention -> partials; 3) Wm conv with fused combine (no MSG pass)
    if (NS == 2) {
        attn_kernel<2><<<dim3(32, H_ * 2, B_), blk, 0, stream>>>(Qh, Kh, Vh, edge, OP, ML);
        conv_msg_kernel<2><<<gD, blk, 0, stream>>>(OP, ML, Wm, bm, MES);
    } else {
        attn_kernel<1><<<dim3(32, H_, B_), blk, 0, stream>>>(Qh, Kh, Vh, edge, OP, ML);
        conv_msg_kernel<1><<<gD, blk, 0, stream>>>(OP, ML, Wm, bm, MES);
    }

    // 4) MLP
    conv_mix_kernel<<<g2D, blk, 0, stream>>>(x, D_, MES, D_, W1, b1, H1, 2 * D_, 2 * D_);
    conv_hf_kernel<<<gD, blk, 0, stream>>>(H1, W2, b2, out, D_, 2 * D_);
}